// Round 7
// baseline (401.642 us; speedup 1.0000x reference)
//
#include <hip/hip_runtime.h>
#include <hip/hip_bf16.h>

typedef __hip_bfloat16 bf16;
typedef __bf16 bf16x8 __attribute__((ext_vector_type(8)));
typedef __bf16 bf16x4 __attribute__((ext_vector_type(4)));
typedef float f32x4 __attribute__((ext_vector_type(4)));

static __device__ __forceinline__ f32x4 mfma16(bf16x8 a, bf16x8 b, f32x4 c) {
  return __builtin_amdgcn_mfma_f32_16x16x32_bf16(a, b, c, 0, 0, 0);
}
static __device__ __forceinline__ bf16x8 ld8(const bf16* p) {
  return *reinterpret_cast<const bf16x8*>(p);
}
static __device__ __forceinline__ float toF(float v) { return v; }
static __device__ __forceinline__ float toF(bf16 v) { return __bfloat162float(v); }
static __device__ __forceinline__ void stF(float* p, float v) { *p = v; }
static __device__ __forceinline__ void stF(bf16* p, float v) { *p = __float2bfloat16(v); }

// exact GELU via A&S 7.1.26 erf (|err| < 1.5e-7 -- below bf16 output
// resolution). Branch-free ~14 VALU ops vs libm erff's ~40+ with divergence.
static __device__ __forceinline__ float fast_gelu(float x) {
  float y = fabsf(x) * 0.70710678118654752f;
  float t = 1.0f / fmaf(0.3275911f, y, 1.0f);
  float p = t * fmaf(t, fmaf(t, fmaf(t, fmaf(t, 1.061405429f, -1.453152027f),
                                     1.421413741f), -0.284496736f), 0.254829592f);
  float e = __expf(-y * y);
  float erfv = copysignf(1.0f - p * e, x);
  return 0.5f * x * (1.0f + erfv);
}

typedef __attribute__((address_space(1))) void gvoid;
typedef __attribute__((address_space(3))) void lvoid;
static __device__ __forceinline__ void gl2lds16(const bf16* g, bf16* l) {
  __builtin_amdgcn_global_load_lds((gvoid*)g, (lvoid*)l, 16, 0, 0);
}

// ---------------- fp32 -> bf16 elementwise ----------------
__global__ __launch_bounds__(256) void cvt_kernel(const float* __restrict__ in,
                                                  bf16* __restrict__ out) {
  long i = (long)blockIdx.x * 256 + threadIdx.x;
  float4 v = reinterpret_cast<const float4*>(in)[i];
  bf16x4 o;
  o[0] = __float2bfloat16(v.x); o[1] = __float2bfloat16(v.y);
  o[2] = __float2bfloat16(v.z); o[3] = __float2bfloat16(v.w);
  reinterpret_cast<bf16x4*>(out)[i] = o;
}

// ---------------- ALL weight transposes in ONE dispatch ----------------
__global__ void prep_weights(const float* __restrict__ Wq, const float* __restrict__ Wk,
                             const float* __restrict__ Wv, const float* __restrict__ Wo,
                             const float* __restrict__ W1, const float* __restrict__ W2,
                             bf16* __restrict__ Wtqkv, bf16* __restrict__ WtO,
                             bf16* __restrict__ Wt1, bf16* __restrict__ Wt2) {
  int id = blockIdx.x;
  const float* in;
  bf16* out;
  int K, N, n0, k0;
  if (id < 1024) {
    int which = id >> 8, t = id & 255;
    K = 512; N = 512;
    n0 = (t & 15) * 32; k0 = (t >> 4) * 32;
    if (which == 0)      { in = Wq; out = Wtqkv; }
    else if (which == 1) { in = Wk; out = Wtqkv + (size_t)512 * 512; }
    else if (which == 2) { in = Wv; out = Wtqkv + (size_t)1024 * 512; }
    else                 { in = Wo; out = WtO; }
  } else if (id < 2048) {
    int t = id - 1024;
    in = W1; out = Wt1; K = 512; N = 2048;
    n0 = (t & 63) * 32; k0 = (t >> 6) * 32;
  } else {
    int t = id - 2048;
    in = W2; out = Wt2; K = 2048; N = 512;
    n0 = (t & 15) * 32; k0 = (t >> 4) * 32;
  }
  __shared__ float tile[32][33];
  int tx = threadIdx.x, ty = threadIdx.y;
#pragma unroll
  for (int j = 0; j < 32; j += 8)
    tile[ty + j][tx] = in[(long)(k0 + ty + j) * N + n0 + tx];
  __syncthreads();
#pragma unroll
  for (int j = 0; j < 32; j += 8)
    out[(long)(n0 + ty + j) * K + k0 + tx] = __float2bfloat16(tile[tx][ty + j]);
}

// ---------------- MFMA GEMM: 3-buffer ring, counted vmcnt, raw s_barrier ----------
template <int MODE>
__global__ __launch_bounds__(256) void gemm_kernel(
    const bf16* __restrict__ A, const bf16* __restrict__ Wt,
    const float* __restrict__ b0, const float* __restrict__ b1_,
    const float* __restrict__ b2_, bf16* C0, bf16* C1, bf16* C2,
    int K, int ldc, int mmask, int mshift) {
  __shared__ alignas(16) bf16 As[3][128 * 32];
  __shared__ alignas(16) bf16 Bs[3][128 * 32];
  const int tid = threadIdx.x;
  const int wave = tid >> 6, lane = tid & 63;
  const int lr = lane & 15, lq = lane >> 4;
  const int L = blockIdx.x;
  const int m0 = (L & mmask) * 128, n0 = (L >> mshift) * 128;
  const int wm = (wave >> 1) * 64, wn = (wave & 1) * 64;

  const int srow0 = (wave * 2) * 16 + (lane >> 2);
  const int srow1 = (wave * 2 + 1) * 16 + (lane >> 2);
  const int scol = (lane & 3) * 8;
  const bf16* Ag0 = A + (long)(m0 + srow0) * K + scol;
  const bf16* Ag1 = A + (long)(m0 + srow1) * K + scol;
  const bf16* Bg0 = Wt + (long)(n0 + srow0) * K + scol;
  const bf16* Bg1 = Wt + (long)(n0 + srow1) * K + scol;
  const int so0 = (wave * 2) * 16 * 32;
  const int so1 = (wave * 2 + 1) * 16 * 32;

  f32x4 acc[4][4] = {};

  auto stage = [&](int k0, int buf) {
    gl2lds16(Ag0 + k0, &As[buf][so0]);
    gl2lds16(Ag1 + k0, &As[buf][so1]);
    gl2lds16(Bg0 + k0, &Bs[buf][so0]);
    gl2lds16(Bg1 + k0, &Bs[buf][so1]);
  };

  stage(0, 0);
  stage(32, 1);

  const int nk = K >> 5;   // K is 512 or 2048 -> nk >= 16
  int cur = 0, sb = 2;     // compute buf = t%3, stage buf = (t+2)%3
  for (int t = 0; t < nk; ++t) {
    if (t < nk - 1) {
      asm volatile("s_waitcnt vmcnt(4)" ::: "memory");
    } else {
      asm volatile("s_waitcnt vmcnt(0)" ::: "memory");
    }
    __builtin_amdgcn_s_barrier();
    if (t < nk - 2) stage((t + 2) << 5, sb);

    bf16x8 af[4], bfr[4];
#pragma unroll
    for (int i = 0; i < 4; ++i) af[i] = ld8(&As[cur][(wm + i * 16 + lr) * 32 + lq * 8]);
#pragma unroll
    for (int j = 0; j < 4; ++j) bfr[j] = ld8(&Bs[cur][(wn + j * 16 + lr) * 32 + lq * 8]);
#pragma unroll
    for (int i = 0; i < 4; ++i)
#pragma unroll
      for (int j = 0; j < 4; ++j) acc[i][j] = mfma16(af[i], bfr[j], acc[i][j]);

    cur = (cur == 2) ? 0 : cur + 1;
    sb = (sb == 2) ? 0 : sb + 1;
  }

  const float* bias = b0;
  bf16* C = C0;
  int cb = n0;
  bool vmode = false;
  if (MODE == 2) {
    if (n0 >= 1024)     { bias = b2_; C = C2; cb = n0 - 1024; vmode = true; }
    else if (n0 >= 512) { bias = b1_; C = C1; cb = n0 - 512; }
  }

#pragma unroll
  for (int i = 0; i < 4; ++i) {
#pragma unroll
    for (int j = 0; j < 4; ++j) {
      int col = cb + wn + j * 16 + lr;
      float bv = bias[col];
#pragma unroll
      for (int rr = 0; rr < 4; ++rr) {
        int row = m0 + wm + i * 16 + lq * 4 + rr;
        float v = acc[i][j][rr] + bv;
        if (MODE == 1) v = fast_gelu(v);
        if (MODE == 2 && vmode) {
          int hh = col >> 6, e = col & 63;
          int bb = row >> 10, tok = row & 1023;
          C[(((long)((bb * 8 + hh) * 64 + e)) << 10) + tok] = __float2bfloat16(v);
        } else {
          C[(long)row * ldc + col] = __float2bfloat16(v);
        }
      }
    }
  }
}

// ---------------- split-K flash attention, LDS-staged K/V, 32-key P halves ----------
// R5-proven structure; P buffer shrunk 64x72 -> 64x40 by processing each 64-key
// tile as two 32-key halves (write P-half -> read P-half -> PV-half, same
// sched_barrier pattern, identical MFMA count/math). LDS 68 -> 52 KB =>
// 3 blocks/CU instead of 2 (occupancy was the cap at 17.9%).
__global__ __launch_bounds__(256) void attn_splitk(
    const bf16* __restrict__ Q, const bf16* __restrict__ Km,
    const bf16* __restrict__ Vt, bf16* __restrict__ Op,
    float* __restrict__ lsum) {
  constexpr int SP = 40;
  __shared__ alignas(16) bf16 Pall[4][64 * SP];
  __shared__ alignas(16) bf16 Ks[2][2][64][32];
  __shared__ alignas(16) bf16 Vs[2][2][64][32];
  const int tid = threadIdx.x;
  const int wave = tid >> 6, lane = tid & 63;
  const int lr = lane & 15, lq = lane >> 4;
  const int L = blockIdx.x;
  const int bh = ((L >> 6) << 3) | (L & 7);
  const int qh = (L >> 3) & 7;
  const int qc = qh & 3, half = qh >> 2;
  const int h = bh & 7, b = bh >> 3;
  const int q0 = qc * 256 + wave * 64;
  bf16* P = Pall[wave];
  const float Cc = 0.18033688011112042f;  // (1/8)*log2(e)

  bf16x8 qf[4][2];
#pragma unroll
  for (int qs = 0; qs < 4; ++qs) {
    const bf16* qrow = Q + (long)(b * 1024 + q0 + qs * 16 + lr) * 512 + h * 64;
    qf[qs][0] = ld8(qrow + lq * 8);
    qf[qs][1] = ld8(qrow + 32 + lq * 8);
  }
  const bf16* kbase = Km + (long)(b * 1024 + half * 512) * 512 + h * 64;
  const bf16* vbase = Vt + (long)((b * 8 + h) * 64) * 1024 + half * 512;

  // staging source: row sr = wave*16 + (lane>>2), 16B chunk (lane&3)*8.
  // LDS placement within sub-tile: sr*64B + (lane&3)*16B = wave*1024 + lane*16.
  const int sr = wave * 16 + (lane >> 2);
  const int sc = (lane & 3) * 8;
  const bf16* Kg = kbase + (long)sr * 512 + sc;
  const bf16* Vg = vbase + (long)sr * 1024 + sc;

  auto stage = [&](int kb, int p) {
#pragma unroll
    for (int kk = 0; kk < 2; ++kk)
      gl2lds16(Kg + (long)kb * 64 * 512 + kk * 32, &Ks[p][kk][wave * 16][0]);
#pragma unroll
    for (int kk = 0; kk < 2; ++kk)
      gl2lds16(Vg + kb * 64 + kk * 32, &Vs[p][kk][wave * 16][0]);
  };

  bf16x8 ones;
#pragma unroll
  for (int k = 0; k < 8; ++k) ones[k] = __float2bfloat16(1.0f);

  f32x4 oacc[4][4] = {};
  f32x4 lacc[4] = {};

  stage(0, 0);
  __syncthreads();

  int p = 0;
  for (int kb = 0; kb < 8; ++kb) {
    if (kb < 7) stage(kb + 1, p ^ 1);  // block-uniform; drained by end barrier
#pragma unroll
    for (int hf = 0; hf < 2; ++hf) {
      // QK^T for 32 keys -> P[64][0..31]
#pragma unroll
      for (int kt = 0; kt < 2; ++kt) {
        bf16x8 kf0 = ld8(&Ks[p][0][hf * 32 + kt * 16 + lr][lq * 8]);
        bf16x8 kf1 = ld8(&Ks[p][1][hf * 32 + kt * 16 + lr][lq * 8]);
#pragma unroll
        for (int qs = 0; qs < 4; ++qs) {
          f32x4 t = {};
          t = mfma16(kf0, qf[qs][0], t);
          t = mfma16(kf1, qf[qs][1], t);
          bf16x4 pk;
#pragma unroll
          for (int rr = 0; rr < 4; ++rr) pk[rr] = __float2bfloat16(exp2f(t[rr] * Cc));
          *reinterpret_cast<bf16x4*>(&P[(qs * 16 + lr) * SP + kt * 16 + lq * 4]) = pk;
        }
      }
      __builtin_amdgcn_sched_barrier(0);  // P writes before P reads; caps VGPR
      bf16x8 pf[4];
#pragma unroll
      for (int qs = 0; qs < 4; ++qs) pf[qs] = ld8(&P[(qs * 16 + lr) * SP + lq * 8]);
#pragma unroll
      for (int qs = 0; qs < 4; ++qs) lacc[qs] = mfma16(pf[qs], ones, lacc[qs]);
#pragma unroll
      for (int j0 = 0; j0 < 4; ++j0) {
        bf16x8 vf = ld8(&Vs[p][hf][j0 * 16 + lr][lq * 8]);
#pragma unroll
        for (int qs = 0; qs < 4; ++qs)
          oacc[qs][j0] = mfma16(pf[qs], vf, oacc[qs][j0]);
      }
      __builtin_amdgcn_sched_barrier(0);  // P reads before next half's P writes
    }
    __syncthreads();  // drains vmcnt: buf p^1 staged; readers of buf p done
    p ^= 1;
  }

  bf16* Oh = Op + (size_t)half * ((size_t)16384 * 512);
#pragma unroll
  for (int qs = 0; qs < 4; ++qs)
#pragma unroll
    for (int rr = 0; rr < 4; ++rr)
#pragma unroll
      for (int j0 = 0; j0 < 4; ++j0)
        Oh[(long)(b * 1024 + q0 + qs * 16 + lq * 4 + rr) * 512 + h * 64 + j0 * 16 + lr] =
            __float2bfloat16(oacc[qs][j0][rr]);
  if (lr == 0) {
    float* lp = lsum + (size_t)half * 131072 + ((size_t)(b * 8 + h) << 10);
#pragma unroll
    for (int qs = 0; qs < 4; ++qs)
#pragma unroll
      for (int rr = 0; rr < 4; ++rr)
        lp[q0 + qs * 16 + lq * 4 + rr] = lacc[qs][rr];
  }
}

// ---------------- combine: O = (O0+O1)/(l0+l1), write [tok,512] ----------------
__global__ __launch_bounds__(256) void attn_combine(
    const bf16* __restrict__ Op, const float* __restrict__ lsum,
    bf16* __restrict__ O) {
  long i = (long)blockIdx.x * 256 + threadIdx.x;
  long idx = i * 8;
  int tok = (int)(idx >> 9), col = (int)(idx & 511);
  int b = tok >> 10, q = tok & 1023, h = col >> 6;
  int li = (b * 8 + h) * 1024 + q;
  float inv = 1.0f / (lsum[li] + lsum[131072 + li]);
  bf16x8 a = ld8(Op + idx);
  bf16x8 c = ld8(Op + (size_t)16384 * 512 + idx);
  bf16x8 o;
#pragma unroll
  for (int k = 0; k < 8; ++k)
    o[k] = __float2bfloat16(((float)a[k] + (float)c[k]) * inv);
  *reinterpret_cast<bf16x8*>(O + idx) = o;
}

// ---------------- fallback attention (round-8 + ones-MFMA l) ----------------
__global__ __launch_bounds__(256) void attn_kernel(
    const bf16* Q, const bf16* __restrict__ Km,
    const bf16* __restrict__ Vt, bf16* O) {
  constexpr int SP = 72;
  __shared__ alignas(16) bf16 Pall[4][64 * SP];
  const int tid = threadIdx.x;
  const int wave = tid >> 6, lane = tid & 63;
  const int lr = lane & 15, lq = lane >> 4;
  const int L = blockIdx.x;
  const int bh = ((L >> 5) << 3) | (L & 7);
  const int qc = (L >> 3) & 3;
  const int h = bh & 7, b = bh >> 3;
  const int q0 = qc * 256 + wave * 64;
  bf16* P = Pall[wave];
  const float Cc = 0.18033688011112042f;

  bf16x8 qf[4][2];
#pragma unroll
  for (int qs = 0; qs < 4; ++qs) {
    const bf16* qrow = Q + (long)(b * 1024 + q0 + qs * 16 + lr) * 512 + h * 64;
    qf[qs][0] = ld8(qrow + lq * 8);
    qf[qs][1] = ld8(qrow + 32 + lq * 8);
  }
  const bf16* kbase = Km + (long)(b * 1024) * 512 + h * 64;
  const bf16* vbase = Vt + (long)((b * 8 + h) * 64) * 1024;

  bf16x8 ones;
#pragma unroll
  for (int k = 0; k < 8; ++k) ones[k] = __float2bfloat16(1.0f);

  f32x4 oacc[4][4] = {};
  f32x4 lacc[4] = {};

  for (int kb = 0; kb < 16; ++kb) {
#pragma unroll
    for (int kt = 0; kt < 4; ++kt) {
      const bf16* krow = kbase + (long)(kb * 64 + kt * 16 + lr) * 512;
      bf16x8 kf0 = ld8(krow + lq * 8);
      bf16x8 kf1 = ld8(krow + 32 + lq * 8);
#pragma unroll
      for (int qs = 0; qs < 4; ++qs) {
        f32x4 t = {};
        t = mfma16(kf0, qf[qs][0], t);
        t = mfma16(kf1, qf[qs][1], t);
        bf16x4 pk;
#pragma unroll
        for (int rr = 0; rr < 4; ++rr) pk[rr] = __float2bfloat16(exp2f(t[rr] * Cc));
        *reinterpret_cast<bf16x4*>(&P[(qs * 16 + lr) * SP + kt * 16 + lq * 4]) = pk;
      }
    }
    __builtin_amdgcn_sched_barrier(0);
    bf16x8 pf[4][2];
#pragma unroll
    for (int qs = 0; qs < 4; ++qs) {
      pf[qs][0] = ld8(&P[(qs * 16 + lr) * SP + lq * 8]);
      pf[qs][1] = ld8(&P[(qs * 16 + lr) * SP + 32 + lq * 8]);
    }
#pragma unroll
    for (int qs = 0; qs < 4; ++qs) {
      lacc[qs] = mfma16(pf[qs][0], ones, lacc[qs]);
      lacc[qs] = mfma16(pf[qs][1], ones, lacc[qs]);
    }
#pragma unroll
    for (int j0 = 0; j0 < 4; ++j0) {
      const bf16* vrow = vbase + (long)(j0 * 16 + lr) * 1024 + kb * 64;
      bf16x8 vf0 = ld8(vrow + lq * 8);
      bf16x8 vf1 = ld8(vrow + 32 + lq * 8);
#pragma unroll
      for (int qs = 0; qs < 4; ++qs) {
        oacc[qs][j0] = mfma16(pf[qs][0], vf0, oacc[qs][j0]);
        oacc[qs][j0] = mfma16(pf[qs][1], vf1, oacc[qs][j0]);
      }
    }
    __builtin_amdgcn_sched_barrier(0);
  }

#pragma unroll
  for (int qs = 0; qs < 4; ++qs)
#pragma unroll
    for (int rr = 0; rr < 4; ++rr) {
      float lv = 1.0f / lacc[qs][rr];
#pragma unroll
      for (int j0 = 0; j0 < 4; ++j0)
        O[(long)(b * 1024 + q0 + qs * 16 + lq * 4 + rr) * 512 + h * 64 + j0 * 16 + lr] =
            __float2bfloat16(oacc[qs][j0][rr] * lv);
    }
}

// ---------------- fused residual + LayerNorm over D=512 ----------------
template <typename TX, typename TO>
__global__ __launch_bounds__(256) void add_ln_kernel(
    const TX* __restrict__ X, const bf16* __restrict__ Y,
    const float* __restrict__ g, const float* __restrict__ bb,
    TO* __restrict__ out) {
  const int row = blockIdx.x, t = threadIdx.x;
  __shared__ float s1[4], s2[4];
  long base = (long)row * 512;
  float v0 = toF(X[base + t]) + toF(Y[base + t]);
  float v1 = toF(X[base + 256 + t]) + toF(Y[base + 256 + t]);
  float s = v0 + v1, q = v0 * v0 + v1 * v1;
#pragma unroll
  for (int o = 32; o > 0; o >>= 1) {
    s += __shfl_down(s, o);
    q += __shfl_down(q, o);
  }
  int wv = t >> 6;
  if ((t & 63) == 0) { s1[wv] = s; s2[wv] = q; }
  __syncthreads();
  float St = s1[0] + s1[1] + s1[2] + s1[3];
  float Qt = s2[0] + s2[1] + s2[2] + s2[3];
  float mean = St * (1.f / 512.f);
  float var = Qt * (1.f / 512.f) - mean * mean;
  float rs = rsqrtf(var + 1e-5f);
  stF(&out[base + t], (v0 - mean) * rs * g[t] + bb[t]);
  stF(&out[base + 256 + t], (v1 - mean) * rs * g[256 + t] + bb[256 + t]);
}

// ---------------- launch ----------------
extern "C" void kernel_launch(void* const* d_in, const int* in_sizes, int n_in,
                              void* d_out, int out_size, void* d_ws, size_t ws_size,
                              hipStream_t stream) {
  const float* x    = (const float*)d_in[0];
  const float* Wq   = (const float*)d_in[1];
  const float* bq   = (const float*)d_in[2];
  const float* Wk   = (const float*)d_in[3];
  const float* bk   = (const float*)d_in[4];
  const float* Wv   = (const float*)d_in[5];
  const float* bv   = (const float*)d_in[6];
  const float* Wo   = (const float*)d_in[7];
  const float* bo   = (const float*)d_in[8];
  const float* ln1g = (const float*)d_in[9];
  const float* ln1b = (const float*)d_in[10];
  const float* W1   = (const float*)d_in[11];
  const float* b1   = (const float*)d_in[12];
  const float* W2   = (const float*)d_in[13];
  const float* b2   = (const float*)d_in[14];
  const float* ln2g = (const float*)d_in[15];
  const float* ln2b = (const float*)d_in[16];
  float* out = (float*)d_out;

  char* ws = (char*)d_ws;
  size_t off = 0;
  auto alloc = [&](size_t bytes) {
    char* p = ws + off;
    off += (bytes + 255) & ~(size_t)255;
    return (bf16*)p;
  };
  bf16* Wtqkv = alloc((size_t)1536 * 512 * 2);
  bf16* WtO   = alloc((size_t)512 * 512 * 2);
  bf16* Wt1   = alloc((size_t)512 * 2048 * 2);
  bf16* Wt2   = alloc((size_t)2048 * 512 * 2);
  const size_t SB = (size_t)16384 * 512 * 2;  // 16 MB

  dim3 tb(32, 8);

  if (ws_size >= (size_t)104 * 1024 * 1024) {
    // [W 6][xb 16 (x bf16 -> ff2)][kb 16 (K -> x1)]
    // [qb 16 (Q -> O -> ff1)][vtb 16 (Vt -> att -> ff1)]
    // [p0 16 (Opart0 -> ff1)][p1 16 (Opart1 -> ff1)][l 1]   = 103 MB
    bf16* xb  = alloc(SB);
    bf16* kb  = alloc(SB);
    bf16* qb  = alloc(SB);
    bf16* vtb = alloc(SB);
    bf16* p0  = alloc(SB);
    bf16* p1  = alloc(SB);
    float* lsum = (float*)alloc((size_t)2 * 131072 * 4);
    bf16* ff1 = qb;   // 64 MB contiguous qb|vtb|p0|p1
    bf16* ff2 = xb;
    (void)p1;

    cvt_kernel<<<8192, 256, 0, stream>>>(x, xb);
    prep_weights<<<3072, tb, 0, stream>>>(Wq, Wk, Wv, Wo, W1, W2,
                                          Wtqkv, WtO, Wt1, Wt2);
    gemm_kernel<2><<<1536, 256, 0, stream>>>(xb, Wtqkv, bq, bk, bv,
                                             qb, kb, vtb, 512, 512, 127, 7);
    attn_splitk<<<1024, 256, 0, stream>>>(qb, kb, vtb, p0, lsum);
    attn_combine<<<4096, 256, 0, stream>>>(p0, lsum, qb);   // O -> qb (Q dead)
    gemm_kernel<0><<<512, 256, 0, stream>>>(qb, WtO, bo, nullptr, nullptr,
                                            vtb, nullptr, nullptr, 512, 512, 127, 7);
    add_ln_kernel<bf16, bf16><<<16384, 256, 0, stream>>>(xb, vtb, ln1g, ln1b, kb);
    gemm_kernel<1><<<2048, 256, 0, stream>>>(kb, Wt1, b1, nullptr, nullptr,
                                             ff1, nullptr, nullptr, 512, 2048, 127, 7);
    gemm_kernel<0><<<512, 256, 0, stream>>>(ff1, Wt2, b2, nullptr, nullptr,
                                            ff2, nullptr, nullptr, 2048, 512, 127, 7);
    add_ln_kernel<bf16, float><<<16384, 256, 0, stream>>>(kb, ff2, ln2g, ln2b, out);
  } else {
    // 78 MB fallback (round-8 structure)
    bf16* xb  = alloc(SB);
    bf16* kb  = alloc(SB);       // K, then x1
    bf16* qb  = alloc(SB);       // Q, then O, then ff1 lo
    bf16* vtb = alloc(SB);       // Vt, then att, then ff1 hi
    bf16* fb  = alloc(SB / 2);   // ff2 half
    bf16* ff1 = qb;              // 32MB contiguous qb+vtb

    cvt_kernel<<<8192, 256, 0, stream>>>(x, xb);
    prep_weights<<<3072, tb, 0, stream>>>(Wq, Wk, Wv, Wo, W1, W2,
                                          Wtqkv, WtO, Wt1, Wt2);
    gemm_kernel<2><<<1536, 256, 0, stream>>>(xb, Wtqkv, bq, bk, bv,
                                             qb, kb, vtb, 512, 512, 127, 7);
    attn_kernel<<<512, 256, 0, stream>>>(qb, kb, vtb, qb);
    gemm_kernel<0><<<512, 256, 0, stream>>>(qb, WtO, bo, nullptr, nullptr,
                                            vtb, nullptr, nullptr, 512, 512, 127, 7);
    add_ln_kernel<bf16, bf16><<<16384, 256, 0, stream>>>(xb, vtb, ln1g, ln1b, kb);

    for (int hh = 0; hh < 2; ++hh) {
      const bf16* x1h = kb + (size_t)hh * 8192 * 512;
      gemm_kernel<1><<<1024, 256, 0, stream>>>(x1h, Wt1, b1, nullptr, nullptr,
                                               ff1, nullptr, nullptr, 512, 2048, 63, 6);
      gemm_kernel<0><<<256, 256, 0, stream>>>(ff1, Wt2, b2, nullptr, nullptr,
                                              fb, nullptr, nullptr, 2048, 512, 63, 6);
      add_ln_kernel<bf16, float><<<8192, 256, 0, stream>>>(x1h, fb, ln2g, ln2b,
                                                           out + (size_t)hh * 8192 * 512);
    }
  }
}

// Round 8
// 379.799 us; speedup vs baseline: 1.0575x; 1.0575x over previous
//
#include <hip/hip_runtime.h>
#include <hip/hip_bf16.h>

typedef __hip_bfloat16 bf16;
typedef __bf16 bf16x8 __attribute__((ext_vector_type(8)));
typedef __bf16 bf16x4 __attribute__((ext_vector_type(4)));
typedef float f32x4 __attribute__((ext_vector_type(4)));

static __device__ __forceinline__ f32x4 mfma16(bf16x8 a, bf16x8 b, f32x4 c) {
  return __builtin_amdgcn_mfma_f32_16x16x32_bf16(a, b, c, 0, 0, 0);
}
static __device__ __forceinline__ bf16x8 ld8(const bf16* p) {
  return *reinterpret_cast<const bf16x8*>(p);
}
static __device__ __forceinline__ float toF(float v) { return v; }
static __device__ __forceinline__ float toF(bf16 v) { return __bfloat162float(v); }
static __device__ __forceinline__ void stF(float* p, float v) { *p = v; }
static __device__ __forceinline__ void stF(bf16* p, float v) { *p = __float2bfloat16(v); }

typedef __attribute__((address_space(1))) void gvoid;
typedef __attribute__((address_space(3))) void lvoid;
static __device__ __forceinline__ void gl2lds16(const bf16* g, bf16* l) {
  __builtin_amdgcn_global_load_lds((gvoid*)g, (lvoid*)l, 16, 0, 0);
}

// ---------------- fused fp32->bf16 cvt + ALL weight transposes, ONE dispatch -------
// Blocks [0,8192): cvt of x (memory-bound). Blocks [8192,11264): weight
// transposes (LDS-bound). Independent work, previously two serial dispatches.
__global__ __launch_bounds__(256) void cvt_prep(
    const float* __restrict__ x, bf16* __restrict__ xb,
    const float* __restrict__ Wq, const float* __restrict__ Wk,
    const float* __restrict__ Wv, const float* __restrict__ Wo,
    const float* __restrict__ W1, const float* __restrict__ W2,
    bf16* __restrict__ Wtqkv, bf16* __restrict__ WtO,
    bf16* __restrict__ Wt1, bf16* __restrict__ Wt2) {
  int blk = blockIdx.x;
  int tx = threadIdx.x, ty = threadIdx.y;
  if (blk < 8192) {
    int t = ty * 32 + tx;
    long i = (long)blk * 256 + t;
    float4 v = reinterpret_cast<const float4*>(x)[i];
    bf16x4 o;
    o[0] = __float2bfloat16(v.x); o[1] = __float2bfloat16(v.y);
    o[2] = __float2bfloat16(v.z); o[3] = __float2bfloat16(v.w);
    reinterpret_cast<bf16x4*>(xb)[i] = o;
    return;
  }
  int id = blk - 8192;
  const float* in;
  bf16* out;
  int K, N, n0, k0;
  if (id < 1024) {
    int which = id >> 8, t = id & 255;
    K = 512; N = 512;
    n0 = (t & 15) * 32; k0 = (t >> 4) * 32;
    if (which == 0)      { in = Wq; out = Wtqkv; }
    else if (which == 1) { in = Wk; out = Wtqkv + (size_t)512 * 512; }
    else if (which == 2) { in = Wv; out = Wtqkv + (size_t)1024 * 512; }
    else                 { in = Wo; out = WtO; }
  } else if (id < 2048) {
    int t = id - 1024;
    in = W1; out = Wt1; K = 512; N = 2048;
    n0 = (t & 63) * 32; k0 = (t >> 6) * 32;
  } else {
    int t = id - 2048;
    in = W2; out = Wt2; K = 2048; N = 512;
    n0 = (t & 15) * 32; k0 = (t >> 4) * 32;
  }
  __shared__ float tile[32][33];
#pragma unroll
  for (int j = 0; j < 32; j += 8)
    tile[ty + j][tx] = in[(long)(k0 + ty + j) * N + n0 + tx];
  __syncthreads();
#pragma unroll
  for (int j = 0; j < 32; j += 8)
    out[(long)(n0 + ty + j) * K + k0 + tx] = __float2bfloat16(tile[tx][ty + j]);
}

// ---------------- standalone kernels (fallback path) ----------------
__global__ __launch_bounds__(256) void cvt_kernel(const float* __restrict__ in,
                                                  bf16* __restrict__ out) {
  long i = (long)blockIdx.x * 256 + threadIdx.x;
  float4 v = reinterpret_cast<const float4*>(in)[i];
  bf16x4 o;
  o[0] = __float2bfloat16(v.x); o[1] = __float2bfloat16(v.y);
  o[2] = __float2bfloat16(v.z); o[3] = __float2bfloat16(v.w);
  reinterpret_cast<bf16x4*>(out)[i] = o;
}

__global__ void prep_weights(const float* __restrict__ Wq, const float* __restrict__ Wk,
                             const float* __restrict__ Wv, const float* __restrict__ Wo,
                             const float* __restrict__ W1, const float* __restrict__ W2,
                             bf16* __restrict__ Wtqkv, bf16* __restrict__ WtO,
                             bf16* __restrict__ Wt1, bf16* __restrict__ Wt2) {
  int id = blockIdx.x;
  const float* in;
  bf16* out;
  int K, N, n0, k0;
  if (id < 1024) {
    int which = id >> 8, t = id & 255;
    K = 512; N = 512;
    n0 = (t & 15) * 32; k0 = (t >> 4) * 32;
    if (which == 0)      { in = Wq; out = Wtqkv; }
    else if (which == 1) { in = Wk; out = Wtqkv + (size_t)512 * 512; }
    else if (which == 2) { in = Wv; out = Wtqkv + (size_t)1024 * 512; }
    else                 { in = Wo; out = WtO; }
  } else if (id < 2048) {
    int t = id - 1024;
    in = W1; out = Wt1; K = 512; N = 2048;
    n0 = (t & 63) * 32; k0 = (t >> 6) * 32;
  } else {
    int t = id - 2048;
    in = W2; out = Wt2; K = 2048; N = 512;
    n0 = (t & 15) * 32; k0 = (t >> 4) * 32;
  }
  __shared__ float tile[32][33];
  int tx = threadIdx.x, ty = threadIdx.y;
#pragma unroll
  for (int j = 0; j < 32; j += 8)
    tile[ty + j][tx] = in[(long)(k0 + ty + j) * N + n0 + tx];
  __syncthreads();
#pragma unroll
  for (int j = 0; j < 32; j += 8)
    out[(long)(n0 + ty + j) * K + k0 + tx] = __float2bfloat16(tile[tx][ty + j]);
}

// ---------------- MFMA GEMM: 3-buffer ring, counted vmcnt, raw s_barrier ----------
template <int MODE>
__global__ __launch_bounds__(256) void gemm_kernel(
    const bf16* __restrict__ A, const bf16* __restrict__ Wt,
    const float* __restrict__ b0, const float* __restrict__ b1_,
    const float* __restrict__ b2_, bf16* C0, bf16* C1, bf16* C2,
    int K, int ldc, int mmask, int mshift) {
  __shared__ alignas(16) bf16 As[3][128 * 32];
  __shared__ alignas(16) bf16 Bs[3][128 * 32];
  const int tid = threadIdx.x;
  const int wave = tid >> 6, lane = tid & 63;
  const int lr = lane & 15, lq = lane >> 4;
  const int L = blockIdx.x;
  const int m0 = (L & mmask) * 128, n0 = (L >> mshift) * 128;
  const int wm = (wave >> 1) * 64, wn = (wave & 1) * 64;

  const int srow0 = (wave * 2) * 16 + (lane >> 2);
  const int srow1 = (wave * 2 + 1) * 16 + (lane >> 2);
  const int scol = (lane & 3) * 8;
  const bf16* Ag0 = A + (long)(m0 + srow0) * K + scol;
  const bf16* Ag1 = A + (long)(m0 + srow1) * K + scol;
  const bf16* Bg0 = Wt + (long)(n0 + srow0) * K + scol;
  const bf16* Bg1 = Wt + (long)(n0 + srow1) * K + scol;
  const int so0 = (wave * 2) * 16 * 32;
  const int so1 = (wave * 2 + 1) * 16 * 32;

  f32x4 acc[4][4] = {};

  auto stage = [&](int k0, int buf) {
    gl2lds16(Ag0 + k0, &As[buf][so0]);
    gl2lds16(Ag1 + k0, &As[buf][so1]);
    gl2lds16(Bg0 + k0, &Bs[buf][so0]);
    gl2lds16(Bg1 + k0, &Bs[buf][so1]);
  };

  stage(0, 0);
  stage(32, 1);

  const int nk = K >> 5;   // K is 512 or 2048 -> nk >= 16
  int cur = 0, sb = 2;     // compute buf = t%3, stage buf = (t+2)%3
  for (int t = 0; t < nk; ++t) {
    if (t < nk - 1) {
      asm volatile("s_waitcnt vmcnt(4)" ::: "memory");
    } else {
      asm volatile("s_waitcnt vmcnt(0)" ::: "memory");
    }
    __builtin_amdgcn_s_barrier();
    if (t < nk - 2) stage((t + 2) << 5, sb);

    bf16x8 af[4], bfr[4];
#pragma unroll
    for (int i = 0; i < 4; ++i) af[i] = ld8(&As[cur][(wm + i * 16 + lr) * 32 + lq * 8]);
#pragma unroll
    for (int j = 0; j < 4; ++j) bfr[j] = ld8(&Bs[cur][(wn + j * 16 + lr) * 32 + lq * 8]);
#pragma unroll
    for (int i = 0; i < 4; ++i)
#pragma unroll
      for (int j = 0; j < 4; ++j) acc[i][j] = mfma16(af[i], bfr[j], acc[i][j]);

    cur = (cur == 2) ? 0 : cur + 1;
    sb = (sb == 2) ? 0 : sb + 1;
  }

  const float* bias = b0;
  bf16* C = C0;
  int cb = n0;
  bool vmode = false;
  if (MODE == 2) {
    if (n0 >= 1024)     { bias = b2_; C = C2; cb = n0 - 1024; vmode = true; }
    else if (n0 >= 512) { bias = b1_; C = C1; cb = n0 - 512; }
  }

#pragma unroll
  for (int i = 0; i < 4; ++i) {
#pragma unroll
    for (int j = 0; j < 4; ++j) {
      int col = cb + wn + j * 16 + lr;
      float bv = bias[col];
#pragma unroll
      for (int rr = 0; rr < 4; ++rr) {
        int row = m0 + wm + i * 16 + lq * 4 + rr;
        float v = acc[i][j][rr] + bv;
        if (MODE == 1) v = 0.5f * v * (1.0f + erff(v * 0.70710678118654752f));
        if (MODE == 2 && vmode) {
          int hh = col >> 6, e = col & 63;
          int bb = row >> 10, tok = row & 1023;
          C[(((long)((bb * 8 + hh) * 64 + e)) << 10) + tok] = __float2bfloat16(v);
        } else {
          C[(long)row * ldc + col] = __float2bfloat16(v);
        }
      }
    }
  }
}

// ---------------- fused flash attention: LDS-staged K/V, no split-K ----------------
// R5/R6-proven splitk loop body over the FULL key range (kb 0..15); split-K's
// extra block parallelism is moot now that LDS (69.6 KB) caps residency at
// 2 blocks/CU either way -- grid 512 = exactly 2/CU, same 8 waves/CU steady
// state. Eliminates 64 MB of partial-O writes + the 80 MB combine dispatch.
// Normalizes in-register (1/lacc) and writes O in place over Q (each wave
// reads its own Q rows into registers first; writes touch only those rows).
__global__ __launch_bounds__(256) void attn_fused(
    const bf16* __restrict__ Q, const bf16* __restrict__ Km,
    const bf16* __restrict__ Vt, bf16* __restrict__ O) {
  constexpr int SP = 72;
  __shared__ alignas(16) bf16 Pall[4][64 * SP];
  __shared__ alignas(16) bf16 Ks[2][2][64][32];
  __shared__ alignas(16) bf16 Vs[2][2][64][32];
  const int tid = threadIdx.x;
  const int wave = tid >> 6, lane = tid & 63;
  const int lr = lane & 15, lq = lane >> 4;
  const int L = blockIdx.x;
  const int bh = ((L >> 5) << 3) | (L & 7);
  const int qc = (L >> 3) & 3;
  const int h = bh & 7, b = bh >> 3;
  const int q0 = qc * 256 + wave * 64;
  bf16* P = Pall[wave];
  const float Cc = 0.18033688011112042f;  // (1/8)*log2(e)

  bf16x8 qf[4][2];
#pragma unroll
  for (int qs = 0; qs < 4; ++qs) {
    const bf16* qrow = Q + (long)(b * 1024 + q0 + qs * 16 + lr) * 512 + h * 64;
    qf[qs][0] = ld8(qrow + lq * 8);
    qf[qs][1] = ld8(qrow + 32 + lq * 8);
  }
  const bf16* kbase = Km + (long)(b * 1024) * 512 + h * 64;
  const bf16* vbase = Vt + (long)((b * 8 + h) * 64) * 1024;

  // staging source: row sr = wave*16 + (lane>>2), 16B chunk (lane&3)*8.
  // LDS placement within sub-tile: sr*64B + (lane&3)*16B = wave*1024 + lane*16.
  const int sr = wave * 16 + (lane >> 2);
  const int sc = (lane & 3) * 8;
  const bf16* Kg = kbase + (long)sr * 512 + sc;
  const bf16* Vg = vbase + (long)sr * 1024 + sc;

  auto stage = [&](int kb, int p) {
#pragma unroll
    for (int kk = 0; kk < 2; ++kk)
      gl2lds16(Kg + (long)kb * 64 * 512 + kk * 32, &Ks[p][kk][wave * 16][0]);
#pragma unroll
    for (int kk = 0; kk < 2; ++kk)
      gl2lds16(Vg + kb * 64 + kk * 32, &Vs[p][kk][wave * 16][0]);
  };

  bf16x8 ones;
#pragma unroll
  for (int k = 0; k < 8; ++k) ones[k] = __float2bfloat16(1.0f);

  f32x4 oacc[4][4] = {};
  f32x4 lacc[4] = {};

  stage(0, 0);
  __syncthreads();

  int p = 0;
  for (int kb = 0; kb < 16; ++kb) {
    if (kb < 15) stage(kb + 1, p ^ 1);  // block-uniform; drained by end barrier
#pragma unroll
    for (int kt = 0; kt < 4; ++kt) {
      bf16x8 kf0 = ld8(&Ks[p][0][kt * 16 + lr][lq * 8]);
      bf16x8 kf1 = ld8(&Ks[p][1][kt * 16 + lr][lq * 8]);
#pragma unroll
      for (int qs = 0; qs < 4; ++qs) {
        f32x4 t = {};
        t = mfma16(kf0, qf[qs][0], t);
        t = mfma16(kf1, qf[qs][1], t);
        bf16x4 pk;
#pragma unroll
        for (int rr = 0; rr < 4; ++rr) pk[rr] = __float2bfloat16(exp2f(t[rr] * Cc));
        *reinterpret_cast<bf16x4*>(&P[(qs * 16 + lr) * SP + kt * 16 + lq * 4]) = pk;
      }
    }
    __builtin_amdgcn_sched_barrier(0);  // P writes before P reads; caps VGPR
    bf16x8 pf[4][2];
#pragma unroll
    for (int qs = 0; qs < 4; ++qs) {
      pf[qs][0] = ld8(&P[(qs * 16 + lr) * SP + lq * 8]);
      pf[qs][1] = ld8(&P[(qs * 16 + lr) * SP + 32 + lq * 8]);
    }
#pragma unroll
    for (int qs = 0; qs < 4; ++qs) {
      lacc[qs] = mfma16(pf[qs][0], ones, lacc[qs]);
      lacc[qs] = mfma16(pf[qs][1], ones, lacc[qs]);
    }
#pragma unroll
    for (int j0 = 0; j0 < 4; ++j0) {
      bf16x8 vf0 = ld8(&Vs[p][0][j0 * 16 + lr][lq * 8]);
      bf16x8 vf1 = ld8(&Vs[p][1][j0 * 16 + lr][lq * 8]);
#pragma unroll
      for (int qs = 0; qs < 4; ++qs) {
        oacc[qs][j0] = mfma16(pf[qs][0], vf0, oacc[qs][j0]);
        oacc[qs][j0] = mfma16(pf[qs][1], vf1, oacc[qs][j0]);
      }
    }
    __builtin_amdgcn_sched_barrier(0);  // P reads before next iter's P writes
    __syncthreads();  // drains vmcnt: buf p^1 staged; readers of buf p done
    p ^= 1;
  }

#pragma unroll
  for (int qs = 0; qs < 4; ++qs)
#pragma unroll
    for (int rr = 0; rr < 4; ++rr) {
      float lv = 1.0f / lacc[qs][rr];
#pragma unroll
      for (int j0 = 0; j0 < 4; ++j0)
        O[(long)(b * 1024 + q0 + qs * 16 + lq * 4 + rr) * 512 + h * 64 + j0 * 16 + lr] =
            __float2bfloat16(oacc[qs][j0][rr] * lv);
    }
}

// ---------------- fallback attention (round-8 + ones-MFMA l) ----------------
__global__ __launch_bounds__(256) void attn_kernel(
    const bf16* Q, const bf16* __restrict__ Km,
    const bf16* __restrict__ Vt, bf16* O) {
  constexpr int SP = 72;
  __shared__ alignas(16) bf16 Pall[4][64 * SP];
  const int tid = threadIdx.x;
  const int wave = tid >> 6, lane = tid & 63;
  const int lr = lane & 15, lq = lane >> 4;
  const int L = blockIdx.x;
  const int bh = ((L >> 5) << 3) | (L & 7);
  const int qc = (L >> 3) & 3;
  const int h = bh & 7, b = bh >> 3;
  const int q0 = qc * 256 + wave * 64;
  bf16* P = Pall[wave];
  const float Cc = 0.18033688011112042f;

  bf16x8 qf[4][2];
#pragma unroll
  for (int qs = 0; qs < 4; ++qs) {
    const bf16* qrow = Q + (long)(b * 1024 + q0 + qs * 16 + lr) * 512 + h * 64;
    qf[qs][0] = ld8(qrow + lq * 8);
    qf[qs][1] = ld8(qrow + 32 + lq * 8);
  }
  const bf16* kbase = Km + (long)(b * 1024) * 512 + h * 64;
  const bf16* vbase = Vt + (long)((b * 8 + h) * 64) * 1024;

  bf16x8 ones;
#pragma unroll
  for (int k = 0; k < 8; ++k) ones[k] = __float2bfloat16(1.0f);

  f32x4 oacc[4][4] = {};
  f32x4 lacc[4] = {};

  for (int kb = 0; kb < 16; ++kb) {
#pragma unroll
    for (int kt = 0; kt < 4; ++kt) {
      const bf16* krow = kbase + (long)(kb * 64 + kt * 16 + lr) * 512;
      bf16x8 kf0 = ld8(krow + lq * 8);
      bf16x8 kf1 = ld8(krow + 32 + lq * 8);
#pragma unroll
      for (int qs = 0; qs < 4; ++qs) {
        f32x4 t = {};
        t = mfma16(kf0, qf[qs][0], t);
        t = mfma16(kf1, qf[qs][1], t);
        bf16x4 pk;
#pragma unroll
        for (int rr = 0; rr < 4; ++rr) pk[rr] = __float2bfloat16(exp2f(t[rr] * Cc));
        *reinterpret_cast<bf16x4*>(&P[(qs * 16 + lr) * SP + kt * 16 + lq * 4]) = pk;
      }
    }
    __builtin_amdgcn_sched_barrier(0);
    bf16x8 pf[4][2];
#pragma unroll
    for (int qs = 0; qs < 4; ++qs) {
      pf[qs][0] = ld8(&P[(qs * 16 + lr) * SP + lq * 8]);
      pf[qs][1] = ld8(&P[(qs * 16 + lr) * SP + 32 + lq * 8]);
    }
#pragma unroll
    for (int qs = 0; qs < 4; ++qs) {
      lacc[qs] = mfma16(pf[qs][0], ones, lacc[qs]);
      lacc[qs] = mfma16(pf[qs][1], ones, lacc[qs]);
    }
#pragma unroll
    for (int j0 = 0; j0 < 4; ++j0) {
      const bf16* vrow = vbase + (long)(j0 * 16 + lr) * 1024 + kb * 64;
      bf16x8 vf0 = ld8(vrow + lq * 8);
      bf16x8 vf1 = ld8(vrow + 32 + lq * 8);
#pragma unroll
      for (int qs = 0; qs < 4; ++qs) {
        oacc[qs][j0] = mfma16(pf[qs][0], vf0, oacc[qs][j0]);
        oacc[qs][j0] = mfma16(pf[qs][1], vf1, oacc[qs][j0]);
      }
    }
    __builtin_amdgcn_sched_barrier(0);
  }

#pragma unroll
  for (int qs = 0; qs < 4; ++qs)
#pragma unroll
    for (int rr = 0; rr < 4; ++rr) {
      float lv = 1.0f / lacc[qs][rr];
#pragma unroll
      for (int j0 = 0; j0 < 4; ++j0)
        O[(long)(b * 1024 + q0 + qs * 16 + lq * 4 + rr) * 512 + h * 64 + j0 * 16 + lr] =
            __float2bfloat16(oacc[qs][j0][rr] * lv);
    }
}

// ---------------- fused residual + LayerNorm over D=512 ----------------
template <typename TX, typename TO>
__global__ __launch_bounds__(256) void add_ln_kernel(
    const TX* __restrict__ X, const bf16* __restrict__ Y,
    const float* __restrict__ g, const float* __restrict__ bb,
    TO* __restrict__ out) {
  const int row = blockIdx.x, t = threadIdx.x;
  __shared__ float s1[4], s2[4];
  long base = (long)row * 512;
  float v0 = toF(X[base + t]) + toF(Y[base + t]);
  float v1 = toF(X[base + 256 + t]) + toF(Y[base + 256 + t]);
  float s = v0 + v1, q = v0 * v0 + v1 * v1;
#pragma unroll
  for (int o = 32; o > 0; o >>= 1) {
    s += __shfl_down(s, o);
    q += __shfl_down(q, o);
  }
  int wv = t >> 6;
  if ((t & 63) == 0) { s1[wv] = s; s2[wv] = q; }
  __syncthreads();
  float St = s1[0] + s1[1] + s1[2] + s1[3];
  float Qt = s2[0] + s2[1] + s2[2] + s2[3];
  float mean = St * (1.f / 512.f);
  float var = Qt * (1.f / 512.f) - mean * mean;
  float rs = rsqrtf(var + 1e-5f);
  stF(&out[base + t], (v0 - mean) * rs * g[t] + bb[t]);
  stF(&out[base + 256 + t], (v1 - mean) * rs * g[256 + t] + bb[256 + t]);
}

// ---------------- launch ----------------
extern "C" void kernel_launch(void* const* d_in, const int* in_sizes, int n_in,
                              void* d_out, int out_size, void* d_ws, size_t ws_size,
                              hipStream_t stream) {
  const float* x    = (const float*)d_in[0];
  const float* Wq   = (const float*)d_in[1];
  const float* bq   = (const float*)d_in[2];
  const float* Wk   = (const float*)d_in[3];
  const float* bk   = (const float*)d_in[4];
  const float* Wv   = (const float*)d_in[5];
  const float* bv   = (const float*)d_in[6];
  const float* Wo   = (const float*)d_in[7];
  const float* bo   = (const float*)d_in[8];
  const float* ln1g = (const float*)d_in[9];
  const float* ln1b = (const float*)d_in[10];
  const float* W1   = (const float*)d_in[11];
  const float* b1   = (const float*)d_in[12];
  const float* W2   = (const float*)d_in[13];
  const float* b2   = (const float*)d_in[14];
  const float* ln2g = (const float*)d_in[15];
  const float* ln2b = (const float*)d_in[16];
  float* out = (float*)d_out;

  char* ws = (char*)d_ws;
  size_t off = 0;
  auto alloc = [&](size_t bytes) {
    char* p = ws + off;
    off += (bytes + 255) & ~(size_t)255;
    return (bf16*)p;
  };
  bf16* Wtqkv = alloc((size_t)1536 * 512 * 2);
  bf16* WtO   = alloc((size_t)512 * 512 * 2);
  bf16* Wt1   = alloc((size_t)512 * 2048 * 2);
  bf16* Wt2   = alloc((size_t)2048 * 512 * 2);
  const size_t SB = (size_t)16384 * 512 * 2;  // 16 MB

  dim3 tb(32, 8);

  if (ws_size >= (size_t)104 * 1024 * 1024) {
    // [W 6][xb 16 (x bf16 -> ff2)][kb 16 (K -> x1)]
    // [qb 16 (Q -> O -> ff1)][vtb 16 (Vt -> att -> ff1)]
    // [p0 16 (ff1)][p1 16 (ff1)]
    bf16* xb  = alloc(SB);
    bf16* kb  = alloc(SB);
    bf16* qb  = alloc(SB);
    bf16* vtb = alloc(SB);
    bf16* p0  = alloc(SB);
    bf16* p1  = alloc(SB);
    bf16* ff1 = qb;   // 64 MB contiguous qb|vtb|p0|p1
    bf16* ff2 = xb;
    (void)p0; (void)p1;

    cvt_prep<<<11264, tb, 0, stream>>>(x, xb, Wq, Wk, Wv, Wo, W1, W2,
                                       Wtqkv, WtO, Wt1, Wt2);
    gemm_kernel<2><<<1536, 256, 0, stream>>>(xb, Wtqkv, bq, bk, bv,
                                             qb, kb, vtb, 512, 512, 127, 7);
    attn_fused<<<512, 256, 0, stream>>>(qb, kb, vtb, qb);  // in-place: O -> qb
    gemm_kernel<0><<<512, 256, 0, stream>>>(qb, WtO, bo, nullptr, nullptr,
                                            vtb, nullptr, nullptr, 512, 512, 127, 7);
    add_ln_kernel<bf16, bf16><<<16384, 256, 0, stream>>>(xb, vtb, ln1g, ln1b, kb);
    gemm_kernel<1><<<2048, 256, 0, stream>>>(kb, Wt1, b1, nullptr, nullptr,
                                             ff1, nullptr, nullptr, 512, 2048, 127, 7);
    gemm_kernel<0><<<512, 256, 0, stream>>>(ff1, Wt2, b2, nullptr, nullptr,
                                            ff2, nullptr, nullptr, 2048, 512, 127, 7);
    add_ln_kernel<bf16, float><<<16384, 256, 0, stream>>>(kb, ff2, ln2g, ln2b, out);
  } else {
    // 78 MB fallback (round-8 structure)
    bf16* xb  = alloc(SB);
    bf16* kb  = alloc(SB);       // K, then x1
    bf16* qb  = alloc(SB);       // Q, then O, then ff1 lo
    bf16* vtb = alloc(SB);       // Vt, then att, then ff1 hi
    bf16* fb  = alloc(SB / 2);   // ff2 half
    bf16* ff1 = qb;              // 32MB contiguous qb+vtb

    cvt_kernel<<<8192, 256, 0, stream>>>(x, xb);
    prep_weights<<<3072, tb, 0, stream>>>(Wq, Wk, Wv, Wo, W1, W2,
                                          Wtqkv, WtO, Wt1, Wt2);
    gemm_kernel<2><<<1536, 256, 0, stream>>>(xb, Wtqkv, bq, bk, bv,
                                             qb, kb, vtb, 512, 512, 127, 7);
    attn_kernel<<<512, 256, 0, stream>>>(qb, kb, vtb, qb);
    gemm_kernel<0><<<512, 256, 0, stream>>>(qb, WtO, bo, nullptr, nullptr,
                                            vtb, nullptr, nullptr, 512, 512, 127, 7);
    add_ln_kernel<bf16, bf16><<<16384, 256, 0, stream>>>(xb, vtb, ln1g, ln1b, kb);

    for (int hh = 0; hh < 2; ++hh) {
      const bf16* x1h = kb + (size_t)hh * 8192 * 512;
      gemm_kernel<1><<<1024, 256, 0, stream>>>(x1h, Wt1, b1, nullptr, nullptr,
                                               ff1, nullptr, nullptr, 512, 2048, 63, 6);
      gemm_kernel<0><<<256, 256, 0, stream>>>(ff1, Wt2, b2, nullptr, nullptr,
                                              fb, nullptr, nullptr, 2048, 512, 63, 6);
      add_ln_kernel<bf16, float><<<8192, 256, 0, stream>>>(x1h, fb, ln2g, ln2b,
                                                           out + (size_t)hh * 8192 * 512);
    }
  }
}

// Round 9
// 365.150 us; speedup vs baseline: 1.0999x; 1.0401x over previous
//
#include <hip/hip_runtime.h>
#include <hip/hip_bf16.h>

typedef __hip_bfloat16 bf16;
typedef __bf16 bf16x8 __attribute__((ext_vector_type(8)));
typedef __bf16 bf16x4 __attribute__((ext_vector_type(4)));
typedef float f32x4 __attribute__((ext_vector_type(4)));

static __device__ __forceinline__ f32x4 mfma16(bf16x8 a, bf16x8 b, f32x4 c) {
  return __builtin_amdgcn_mfma_f32_16x16x32_bf16(a, b, c, 0, 0, 0);
}
static __device__ __forceinline__ bf16x8 ld8(const bf16* p) {
  return *reinterpret_cast<const bf16x8*>(p);
}
static __device__ __forceinline__ float toF(float v) { return v; }
static __device__ __forceinline__ float toF(bf16 v) { return __bfloat162float(v); }
static __device__ __forceinline__ void stF(float* p, float v) { *p = v; }
static __device__ __forceinline__ void stF(bf16* p, float v) { *p = __float2bfloat16(v); }

typedef __attribute__((address_space(1))) void gvoid;
typedef __attribute__((address_space(3))) void lvoid;
static __device__ __forceinline__ void gl2lds16(const bf16* g, bf16* l) {
  __builtin_amdgcn_global_load_lds((gvoid*)g, (lvoid*)l, 16, 0, 0);
}

// ---------------- fused fp32->bf16 cvt + ALL weight transposes, ONE dispatch -------
__global__ __launch_bounds__(256) void cvt_prep(
    const float* __restrict__ x, bf16* __restrict__ xb,
    const float* __restrict__ Wq, const float* __restrict__ Wk,
    const float* __restrict__ Wv, const float* __restrict__ Wo,
    const float* __restrict__ W1, const float* __restrict__ W2,
    bf16* __restrict__ Wtqkv, bf16* __restrict__ WtO,
    bf16* __restrict__ Wt1, bf16* __restrict__ Wt2) {
  int blk = blockIdx.x;
  int tx = threadIdx.x, ty = threadIdx.y;
  if (blk < 8192) {
    int t = ty * 32 + tx;
    long i = (long)blk * 256 + t;
    float4 v = reinterpret_cast<const float4*>(x)[i];
    bf16x4 o;
    o[0] = __float2bfloat16(v.x); o[1] = __float2bfloat16(v.y);
    o[2] = __float2bfloat16(v.z); o[3] = __float2bfloat16(v.w);
    reinterpret_cast<bf16x4*>(xb)[i] = o;
    return;
  }
  int id = blk - 8192;
  const float* in;
  bf16* out;
  int K, N, n0, k0;
  if (id < 1024) {
    int which = id >> 8, t = id & 255;
    K = 512; N = 512;
    n0 = (t & 15) * 32; k0 = (t >> 4) * 32;
    if (which == 0)      { in = Wq; out = Wtqkv; }
    else if (which == 1) { in = Wk; out = Wtqkv + (size_t)512 * 512; }
    else if (which == 2) { in = Wv; out = Wtqkv + (size_t)1024 * 512; }
    else                 { in = Wo; out = WtO; }
  } else if (id < 2048) {
    int t = id - 1024;
    in = W1; out = Wt1; K = 512; N = 2048;
    n0 = (t & 63) * 32; k0 = (t >> 6) * 32;
  } else {
    int t = id - 2048;
    in = W2; out = Wt2; K = 2048; N = 512;
    n0 = (t & 15) * 32; k0 = (t >> 4) * 32;
  }
  __shared__ float tile[32][33];
#pragma unroll
  for (int j = 0; j < 32; j += 8)
    tile[ty + j][tx] = in[(long)(k0 + ty + j) * N + n0 + tx];
  __syncthreads();
#pragma unroll
  for (int j = 0; j < 32; j += 8)
    out[(long)(n0 + ty + j) * K + k0 + tx] = __float2bfloat16(tile[tx][ty + j]);
}

// ---------------- standalone kernels (fallback path) ----------------
__global__ __launch_bounds__(256) void cvt_kernel(const float* __restrict__ in,
                                                  bf16* __restrict__ out) {
  long i = (long)blockIdx.x * 256 + threadIdx.x;
  float4 v = reinterpret_cast<const float4*>(in)[i];
  bf16x4 o;
  o[0] = __float2bfloat16(v.x); o[1] = __float2bfloat16(v.y);
  o[2] = __float2bfloat16(v.z); o[3] = __float2bfloat16(v.w);
  reinterpret_cast<bf16x4*>(out)[i] = o;
}

__global__ void prep_weights(const float* __restrict__ Wq, const float* __restrict__ Wk,
                             const float* __restrict__ Wv, const float* __restrict__ Wo,
                             const float* __restrict__ W1, const float* __restrict__ W2,
                             bf16* __restrict__ Wtqkv, bf16* __restrict__ WtO,
                             bf16* __restrict__ Wt1, bf16* __restrict__ Wt2) {
  int id = blockIdx.x;
  const float* in;
  bf16* out;
  int K, N, n0, k0;
  if (id < 1024) {
    int which = id >> 8, t = id & 255;
    K = 512; N = 512;
    n0 = (t & 15) * 32; k0 = (t >> 4) * 32;
    if (which == 0)      { in = Wq; out = Wtqkv; }
    else if (which == 1) { in = Wk; out = Wtqkv + (size_t)512 * 512; }
    else if (which == 2) { in = Wv; out = Wtqkv + (size_t)1024 * 512; }
    else                 { in = Wo; out = WtO; }
  } else if (id < 2048) {
    int t = id - 1024;
    in = W1; out = Wt1; K = 512; N = 2048;
    n0 = (t & 63) * 32; k0 = (t >> 6) * 32;
  } else {
    int t = id - 2048;
    in = W2; out = Wt2; K = 2048; N = 512;
    n0 = (t & 15) * 32; k0 = (t >> 4) * 32;
  }
  __shared__ float tile[32][33];
  int tx = threadIdx.x, ty = threadIdx.y;
#pragma unroll
  for (int j = 0; j < 32; j += 8)
    tile[ty + j][tx] = in[(long)(k0 + ty + j) * N + n0 + tx];
  __syncthreads();
#pragma unroll
  for (int j = 0; j < 32; j += 8)
    out[(long)(n0 + ty + j) * K + k0 + tx] = __float2bfloat16(tile[tx][ty + j]);
}

// ---------------- MFMA GEMM: 3-buffer ring, counted vmcnt, raw s_barrier ----------
// MFMA operands SWAPPED (bfr as A, af as B): output fragment then holds, per
// lane, 4 CONSECUTIVE n-columns of one m-row (col=lane&15 maps to the B
// operand's row index -- verified by the QK mapping in attn). Epilogue becomes
// 16x 8B bf16x4 stores + f32x4 bias loads instead of 64x 2B scalar stores.
template <int MODE>
__global__ __launch_bounds__(256) void gemm_kernel(
    const bf16* __restrict__ A, const bf16* __restrict__ Wt,
    const float* __restrict__ b0, const float* __restrict__ b1_,
    const float* __restrict__ b2_, bf16* C0, bf16* C1, bf16* C2,
    int K, int ldc, int mmask, int mshift) {
  __shared__ alignas(16) bf16 As[3][128 * 32];
  __shared__ alignas(16) bf16 Bs[3][128 * 32];
  const int tid = threadIdx.x;
  const int wave = tid >> 6, lane = tid & 63;
  const int lr = lane & 15, lq = lane >> 4;
  const int L = blockIdx.x;
  const int m0 = (L & mmask) * 128, n0 = (L >> mshift) * 128;
  const int wm = (wave >> 1) * 64, wn = (wave & 1) * 64;

  const int srow0 = (wave * 2) * 16 + (lane >> 2);
  const int srow1 = (wave * 2 + 1) * 16 + (lane >> 2);
  const int scol = (lane & 3) * 8;
  const bf16* Ag0 = A + (long)(m0 + srow0) * K + scol;
  const bf16* Ag1 = A + (long)(m0 + srow1) * K + scol;
  const bf16* Bg0 = Wt + (long)(n0 + srow0) * K + scol;
  const bf16* Bg1 = Wt + (long)(n0 + srow1) * K + scol;
  const int so0 = (wave * 2) * 16 * 32;
  const int so1 = (wave * 2 + 1) * 16 * 32;

  f32x4 acc[4][4] = {};

  auto stage = [&](int k0, int buf) {
    gl2lds16(Ag0 + k0, &As[buf][so0]);
    gl2lds16(Ag1 + k0, &As[buf][so1]);
    gl2lds16(Bg0 + k0, &Bs[buf][so0]);
    gl2lds16(Bg1 + k0, &Bs[buf][so1]);
  };

  stage(0, 0);
  stage(32, 1);

  const int nk = K >> 5;   // K is 512 or 2048 -> nk >= 16
  int cur = 0, sb = 2;     // compute buf = t%3, stage buf = (t+2)%3
  for (int t = 0; t < nk; ++t) {
    if (t < nk - 1) {
      asm volatile("s_waitcnt vmcnt(4)" ::: "memory");
    } else {
      asm volatile("s_waitcnt vmcnt(0)" ::: "memory");
    }
    __builtin_amdgcn_s_barrier();
    if (t < nk - 2) stage((t + 2) << 5, sb);

    bf16x8 af[4], bfr[4];
#pragma unroll
    for (int i = 0; i < 4; ++i) af[i] = ld8(&As[cur][(wm + i * 16 + lr) * 32 + lq * 8]);
#pragma unroll
    for (int j = 0; j < 4; ++j) bfr[j] = ld8(&Bs[cur][(wn + j * 16 + lr) * 32 + lq * 8]);
#pragma unroll
    for (int i = 0; i < 4; ++i)
#pragma unroll
      for (int j = 0; j < 4; ++j) acc[i][j] = mfma16(bfr[j], af[i], acc[i][j]);

    cur = (cur == 2) ? 0 : cur + 1;
    sb = (sb == 2) ? 0 : sb + 1;
  }

  const float* bias = b0;
  bf16* C = C0;
  int cb = n0;
  bool vmode = false;
  if (MODE == 2) {
    if (n0 >= 1024)     { bias = b2_; C = C2; cb = n0 - 1024; vmode = true; }
    else if (n0 >= 512) { bias = b1_; C = C1; cb = n0 - 512; }
  }

  // lane holds C[row = m0+wm+i*16+lr][col = cb+wn+j*16+lq*4 + rr], rr=0..3
#pragma unroll
  for (int i = 0; i < 4; ++i) {
    int row = m0 + wm + i * 16 + lr;
    long rb = (long)row * ldc;
#pragma unroll
    for (int j = 0; j < 4; ++j) {
      int col0 = cb + wn + j * 16 + lq * 4;
      f32x4 bv = *reinterpret_cast<const f32x4*>(&bias[col0]);
      if (MODE == 2 && vmode) {
        int hh = col0 >> 6, e0 = col0 & 63;   // same head for rr=0..3
        int bb = row >> 10, tok = row & 1023;
        long vb = (((long)((bb * 8 + hh) * 64 + e0)) << 10) + tok;
#pragma unroll
        for (int rr = 0; rr < 4; ++rr)
          C[vb + ((long)rr << 10)] = __float2bfloat16(acc[i][j][rr] + bv[rr]);
      } else {
        bf16x4 o;
#pragma unroll
        for (int rr = 0; rr < 4; ++rr) {
          float v = acc[i][j][rr] + bv[rr];
          if (MODE == 1) v = 0.5f * v * (1.0f + erff(v * 0.70710678118654752f));
          o[rr] = __float2bfloat16(v);
        }
        *reinterpret_cast<bf16x4*>(&C[rb + col0]) = o;
      }
    }
  }
}

// ---------------- fused flash attention: LDS-staged K/V, 32 q/wave, 3 blocks/CU ----
// R8 structure with per-wave q-tile halved (qs 4->2, qc 4->8, grid 512->1024):
// Pall 36.9->18.4 KB => LDS 51.2 KB => 3 blocks/CU (was LDS+grid capped at 2).
// Staged K/V stays L2-resident per (b,h) (bh in low grid bits), so doubling
// qc doubles only L2-served re-reads, not HBM. PV & lacc MFMAs operand-swapped:
// lane holds O[q=lr][4 consecutive e] -> 8x 8B O-stores, 4 rcps (was 64x2B, 16).
__global__ __launch_bounds__(256) void attn_fused(
    const bf16* __restrict__ Q, const bf16* __restrict__ Km,
    const bf16* __restrict__ Vt, bf16* __restrict__ O) {
  constexpr int SP = 72;
  __shared__ alignas(16) bf16 Pall[4][32 * SP];
  __shared__ alignas(16) bf16 Ks[2][2][64][32];
  __shared__ alignas(16) bf16 Vs[2][2][64][32];
  const int tid = threadIdx.x;
  const int wave = tid >> 6, lane = tid & 63;
  const int lr = lane & 15, lq = lane >> 4;
  const int L = blockIdx.x;
  const int bh = ((L >> 6) << 3) | (L & 7);   // same bh -> same XCD
  const int qc = (L >> 3) & 7;
  const int h = bh & 7, b = bh >> 3;
  const int q0 = qc * 128 + wave * 32;
  bf16* P = Pall[wave];
  const float Cc = 0.18033688011112042f;  // (1/8)*log2(e)

  bf16x8 qf[2][2];
#pragma unroll
  for (int qs = 0; qs < 2; ++qs) {
    const bf16* qrow = Q + (long)(b * 1024 + q0 + qs * 16 + lr) * 512 + h * 64;
    qf[qs][0] = ld8(qrow + lq * 8);
    qf[qs][1] = ld8(qrow + 32 + lq * 8);
  }
  const bf16* kbase = Km + (long)(b * 1024) * 512 + h * 64;
  const bf16* vbase = Vt + (long)((b * 8 + h) * 64) * 1024;

  // staging source: row sr = wave*16 + (lane>>2), 16B chunk (lane&3)*8.
  // LDS placement within sub-tile: sr*64B + (lane&3)*16B = wave*1024 + lane*16.
  const int sr = wave * 16 + (lane >> 2);
  const int sc = (lane & 3) * 8;
  const bf16* Kg = kbase + (long)sr * 512 + sc;
  const bf16* Vg = vbase + (long)sr * 1024 + sc;

  auto stage = [&](int kb, int p) {
#pragma unroll
    for (int kk = 0; kk < 2; ++kk)
      gl2lds16(Kg + (long)kb * 64 * 512 + kk * 32, &Ks[p][kk][wave * 16][0]);
#pragma unroll
    for (int kk = 0; kk < 2; ++kk)
      gl2lds16(Vg + kb * 64 + kk * 32, &Vs[p][kk][wave * 16][0]);
  };

  bf16x8 ones;
#pragma unroll
  for (int k = 0; k < 8; ++k) ones[k] = __float2bfloat16(1.0f);

  f32x4 oacc[2][4] = {};
  f32x4 lacc[2] = {};

  stage(0, 0);
  __syncthreads();

  int p = 0;
  for (int kb = 0; kb < 16; ++kb) {
    if (kb < 15) stage(kb + 1, p ^ 1);  // block-uniform; drained by end barrier
#pragma unroll
    for (int kt = 0; kt < 4; ++kt) {
      bf16x8 kf0 = ld8(&Ks[p][0][kt * 16 + lr][lq * 8]);
      bf16x8 kf1 = ld8(&Ks[p][1][kt * 16 + lr][lq * 8]);
#pragma unroll
      for (int qs = 0; qs < 2; ++qs) {
        f32x4 t = {};
        t = mfma16(kf0, qf[qs][0], t);
        t = mfma16(kf1, qf[qs][1], t);
        bf16x4 pk;
#pragma unroll
        for (int rr = 0; rr < 4; ++rr) pk[rr] = __float2bfloat16(exp2f(t[rr] * Cc));
        *reinterpret_cast<bf16x4*>(&P[(qs * 16 + lr) * SP + kt * 16 + lq * 4]) = pk;
      }
    }
    __builtin_amdgcn_sched_barrier(0);  // P writes before P reads; caps VGPR
    bf16x8 pf[2][2];
#pragma unroll
    for (int qs = 0; qs < 2; ++qs) {
      pf[qs][0] = ld8(&P[(qs * 16 + lr) * SP + lq * 8]);
      pf[qs][1] = ld8(&P[(qs * 16 + lr) * SP + 32 + lq * 8]);
    }
#pragma unroll
    for (int qs = 0; qs < 2; ++qs) {
      lacc[qs] = mfma16(ones, pf[qs][0], lacc[qs]);   // l(q=lr) in every slot
      lacc[qs] = mfma16(ones, pf[qs][1], lacc[qs]);
    }
#pragma unroll
    for (int j0 = 0; j0 < 4; ++j0) {
      bf16x8 vf0 = ld8(&Vs[p][0][j0 * 16 + lr][lq * 8]);
      bf16x8 vf1 = ld8(&Vs[p][1][j0 * 16 + lr][lq * 8]);
#pragma unroll
      for (int qs = 0; qs < 2; ++qs) {
        oacc[qs][j0] = mfma16(vf0, pf[qs][0], oacc[qs][j0]);  // swapped: col=q
        oacc[qs][j0] = mfma16(vf1, pf[qs][1], oacc[qs][j0]);
      }
    }
    __builtin_amdgcn_sched_barrier(0);  // P reads before next iter's P writes
    __syncthreads();  // drains vmcnt: buf p^1 staged; readers of buf p done
    p ^= 1;
  }

  // lane holds O[q = q0+qs*16+lr][e = j0*16 + lq*4 + rr]
#pragma unroll
  for (int qs = 0; qs < 2; ++qs) {
    float lv = 1.0f / lacc[qs][0];
    bf16* orow = O + (long)(b * 1024 + q0 + qs * 16 + lr) * 512 + h * 64 + lq * 4;
#pragma unroll
    for (int j0 = 0; j0 < 4; ++j0) {
      bf16x4 o;
#pragma unroll
      for (int rr = 0; rr < 4; ++rr) o[rr] = __float2bfloat16(oacc[qs][j0][rr] * lv);
      *reinterpret_cast<bf16x4*>(&orow[j0 * 16]) = o;
    }
  }
}

// ---------------- fallback attention (round-8 + ones-MFMA l) ----------------
__global__ __launch_bounds__(256) void attn_kernel(
    const bf16* Q, const bf16* __restrict__ Km,
    const bf16* __restrict__ Vt, bf16* O) {
  constexpr int SP = 72;
  __shared__ alignas(16) bf16 Pall[4][64 * SP];
  const int tid = threadIdx.x;
  const int wave = tid >> 6, lane = tid & 63;
  const int lr = lane & 15, lq = lane >> 4;
  const int L = blockIdx.x;
  const int bh = ((L >> 5) << 3) | (L & 7);
  const int qc = (L >> 3) & 3;
  const int h = bh & 7, b = bh >> 3;
  const int q0 = qc * 256 + wave * 64;
  bf16* P = Pall[wave];
  const float Cc = 0.18033688011112042f;

  bf16x8 qf[4][2];
#pragma unroll
  for (int qs = 0; qs < 4; ++qs) {
    const bf16* qrow = Q + (long)(b * 1024 + q0 + qs * 16 + lr) * 512 + h * 64;
    qf[qs][0] = ld8(qrow + lq * 8);
    qf[qs][1] = ld8(qrow + 32 + lq * 8);
  }
  const bf16* kbase = Km + (long)(b * 1024) * 512 + h * 64;
  const bf16* vbase = Vt + (long)((b * 8 + h) * 64) * 1024;

  bf16x8 ones;
#pragma unroll
  for (int k = 0; k < 8; ++k) ones[k] = __float2bfloat16(1.0f);

  f32x4 oacc[4][4] = {};
  f32x4 lacc[4] = {};

  for (int kb = 0; kb < 16; ++kb) {
#pragma unroll
    for (int kt = 0; kt < 4; ++kt) {
      const bf16* krow = kbase + (long)(kb * 64 + kt * 16 + lr) * 512;
      bf16x8 kf0 = ld8(krow + lq * 8);
      bf16x8 kf1 = ld8(krow + 32 + lq * 8);
#pragma unroll
      for (int qs = 0; qs < 4; ++qs) {
        f32x4 t = {};
        t = mfma16(kf0, qf[qs][0], t);
        t = mfma16(kf1, qf[qs][1], t);
        bf16x4 pk;
#pragma unroll
        for (int rr = 0; rr < 4; ++rr) pk[rr] = __float2bfloat16(exp2f(t[rr] * Cc));
        *reinterpret_cast<bf16x4*>(&P[(qs * 16 + lr) * SP + kt * 16 + lq * 4]) = pk;
      }
    }
    __builtin_amdgcn_sched_barrier(0);
    bf16x8 pf[4][2];
#pragma unroll
    for (int qs = 0; qs < 4; ++qs) {
      pf[qs][0] = ld8(&P[(qs * 16 + lr) * SP + lq * 8]);
      pf[qs][1] = ld8(&P[(qs * 16 + lr) * SP + 32 + lq * 8]);
    }
#pragma unroll
    for (int qs = 0; qs < 4; ++qs) {
      lacc[qs] = mfma16(pf[qs][0], ones, lacc[qs]);
      lacc[qs] = mfma16(pf[qs][1], ones, lacc[qs]);
    }
#pragma unroll
    for (int j0 = 0; j0 < 4; ++j0) {
      const bf16* vrow = vbase + (long)(j0 * 16 + lr) * 1024 + kb * 64;
      bf16x8 vf0 = ld8(vrow + lq * 8);
      bf16x8 vf1 = ld8(vrow + 32 + lq * 8);
#pragma unroll
      for (int qs = 0; qs < 4; ++qs) {
        oacc[qs][j0] = mfma16(pf[qs][0], vf0, oacc[qs][j0]);
        oacc[qs][j0] = mfma16(pf[qs][1], vf1, oacc[qs][j0]);
      }
    }
    __builtin_amdgcn_sched_barrier(0);
  }

#pragma unroll
  for (int qs = 0; qs < 4; ++qs)
#pragma unroll
    for (int rr = 0; rr < 4; ++rr) {
      float lv = 1.0f / lacc[qs][rr];
#pragma unroll
      for (int j0 = 0; j0 < 4; ++j0)
        O[(long)(b * 1024 + q0 + qs * 16 + lq * 4 + rr) * 512 + h * 64 + j0 * 16 + lr] =
            __float2bfloat16(oacc[qs][j0][rr] * lv);
    }
}

// ---------------- fused residual + LayerNorm over D=512 ----------------
template <typename TX, typename TO>
__global__ __launch_bounds__(256) void add_ln_kernel(
    const TX* __restrict__ X, const bf16* __restrict__ Y,
    const float* __restrict__ g, const float* __restrict__ bb,
    TO* __restrict__ out) {
  const int row = blockIdx.x, t = threadIdx.x;
  __shared__ float s1[4], s2[4];
  long base = (long)row * 512;
  float v0 = toF(X[base + t]) + toF(Y[base + t]);
  float v1 = toF(X[base + 256 + t]) + toF(Y[base + 256 + t]);
  float s = v0 + v1, q = v0 * v0 + v1 * v1;
#pragma unroll
  for (int o = 32; o > 0; o >>= 1) {
    s += __shfl_down(s, o);
    q += __shfl_down(q, o);
  }
  int wv = t >> 6;
  if ((t & 63) == 0) { s1[wv] = s; s2[wv] = q; }
  __syncthreads();
  float St = s1[0] + s1[1] + s1[2] + s1[3];
  float Qt = s2[0] + s2[1] + s2[2] + s2[3];
  float mean = St * (1.f / 512.f);
  float var = Qt * (1.f / 512.f) - mean * mean;
  float rs = rsqrtf(var + 1e-5f);
  stF(&out[base + t], (v0 - mean) * rs * g[t] + bb[t]);
  stF(&out[base + 256 + t], (v1 - mean) * rs * g[256 + t] + bb[256 + t]);
}

// ---------------- launch ----------------
extern "C" void kernel_launch(void* const* d_in, const int* in_sizes, int n_in,
                              void* d_out, int out_size, void* d_ws, size_t ws_size,
                              hipStream_t stream) {
  const float* x    = (const float*)d_in[0];
  const float* Wq   = (const float*)d_in[1];
  const float* bq   = (const float*)d_in[2];
  const float* Wk   = (const float*)d_in[3];
  const float* bk   = (const float*)d_in[4];
  const float* Wv   = (const float*)d_in[5];
  const float* bv   = (const float*)d_in[6];
  const float* Wo   = (const float*)d_in[7];
  const float* bo   = (const float*)d_in[8];
  const float* ln1g = (const float*)d_in[9];
  const float* ln1b = (const float*)d_in[10];
  const float* W1   = (const float*)d_in[11];
  const float* b1   = (const float*)d_in[12];
  const float* W2   = (const float*)d_in[13];
  const float* b2   = (const float*)d_in[14];
  const float* ln2g = (const float*)d_in[15];
  const float* ln2b = (const float*)d_in[16];
  float* out = (float*)d_out;

  char* ws = (char*)d_ws;
  size_t off = 0;
  auto alloc = [&](size_t bytes) {
    char* p = ws + off;
    off += (bytes + 255) & ~(size_t)255;
    return (bf16*)p;
  };
  bf16* Wtqkv = alloc((size_t)1536 * 512 * 2);
  bf16* WtO   = alloc((size_t)512 * 512 * 2);
  bf16* Wt1   = alloc((size_t)512 * 2048 * 2);
  bf16* Wt2   = alloc((size_t)2048 * 512 * 2);
  const size_t SB = (size_t)16384 * 512 * 2;  // 16 MB

  dim3 tb(32, 8);

  if (ws_size >= (size_t)104 * 1024 * 1024) {
    bf16* xb  = alloc(SB);
    bf16* kb  = alloc(SB);
    bf16* qb  = alloc(SB);
    bf16* vtb = alloc(SB);
    bf16* p0  = alloc(SB);
    bf16* p1  = alloc(SB);
    bf16* ff1 = qb;   // 64 MB contiguous qb|vtb|p0|p1
    bf16* ff2 = xb;
    (void)p0; (void)p1;

    cvt_prep<<<11264, tb, 0, stream>>>(x, xb, Wq, Wk, Wv, Wo, W1, W2,
                                       Wtqkv, WtO, Wt1, Wt2);
    gemm_kernel<2><<<1536, 256, 0, stream>>>(xb, Wtqkv, bq, bk, bv,
                                             qb, kb, vtb, 512, 512, 127, 7);
    attn_fused<<<1024, 256, 0, stream>>>(qb, kb, vtb, qb);  // in-place: O -> qb
    gemm_kernel<0><<<512, 256, 0, stream>>>(qb, WtO, bo, nullptr, nullptr,
                                            vtb, nullptr, nullptr, 512, 512, 127, 7);
    add_ln_kernel<bf16, bf16><<<16384, 256, 0, stream>>>(xb, vtb, ln1g, ln1b, kb);
    gemm_kernel<1><<<2048, 256, 0, stream>>>(kb, Wt1, b1, nullptr, nullptr,
                                             ff1, nullptr, nullptr, 512, 2048, 127, 7);
    gemm_kernel<0><<<512, 256, 0, stream>>>(ff1, Wt2, b2, nullptr, nullptr,
                                            ff2, nullptr, nullptr, 2048, 512, 127, 7);
    add_ln_kernel<bf16, float><<<16384, 256, 0, stream>>>(kb, ff2, ln2g, ln2b, out);
  } else {
    bf16* xb  = alloc(SB);
    bf16* kb  = alloc(SB);       // K, then x1
    bf16* qb  = alloc(SB);       // Q, then O, then ff1 lo
    bf16* vtb = alloc(SB);       // Vt, then att, then ff1 hi
    bf16* fb  = alloc(SB / 2);   // ff2 half
    bf16* ff1 = qb;              // 32MB contiguous qb+vtb

    cvt_kernel<<<8192, 256, 0, stream>>>(x, xb);
    prep_weights<<<3072, tb, 0, stream>>>(Wq, Wk, Wv, Wo, W1, W2,
                                          Wtqkv, WtO, Wt1, Wt2);
    gemm_kernel<2><<<1536, 256, 0, stream>>>(xb, Wtqkv, bq, bk, bv,
                                             qb, kb, vtb, 512, 512, 127, 7);
    attn_kernel<<<512, 256, 0, stream>>>(qb, kb, vtb, qb);
    gemm_kernel<0><<<512, 256, 0, stream>>>(qb, WtO, bo, nullptr, nullptr,
                                            vtb, nullptr, nullptr, 512, 512, 127, 7);
    add_ln_kernel<bf16, bf16><<<16384, 256, 0, stream>>>(xb, vtb, ln1g, ln1b, kb);

    for (int hh = 0; hh < 2; ++hh) {
      const bf16* x1h = kb + (size_t)hh * 8192 * 512;
      gemm_kernel<1><<<1024, 256, 0, stream>>>(x1h, Wt1, b1, nullptr, nullptr,
                                               ff1, nullptr, nullptr, 512, 2048, 63, 6);
      gemm_kernel<0><<<256, 256, 0, stream>>>(ff1, Wt2, b2, nullptr, nullptr,
                                              fb, nullptr, nullptr, 2048, 512, 63, 6);
      add_ln_kernel<bf16, float><<<8192, 256, 0, stream>>>(x1h, fb, ln2g, ln2b,
                                                           out + (size_t)hh * 8192 * 512);
    }
  }
}